// Round 5
// baseline (391.535 us; speedup 1.0000x reference)
//
#include <hip/hip_runtime.h>
#include <hip/hip_fp16.h>
#include <math.h>

#define NPTS 131072
#define RS 264  // LDS row stride in floats; rows 16B-aligned, all phases <=2-way banked

__device__ __forceinline__ float dev_alpha(const float* __restrict__ ap) {
    float x = ap[0];
    float bx = 10.0f * x;
    if (bx > 1.0f) return x;
    float e = expf(fminf(bx, 30.0f));
    return 0.1f * log1pf(e);
}

__device__ __forceinline__ __half2 bch(unsigned u) { return __builtin_bit_cast(__half2, u); }

// -------- 16-point inverse DFT (e^{+i}) in registers, natural in/out --------
__device__ __forceinline__ void fft16_reg(float* re, float* im) {
    #define SW(a,b) { float t=re[a]; re[a]=re[b]; re[b]=t; t=im[a]; im[a]=im[b]; im[b]=t; }
    SW(1,8) SW(2,4) SW(3,12) SW(5,10) SW(7,14) SW(11,13)
    #undef SW
    const float C[8] = {1.f, 0.9238795325112867f, 0.7071067811865476f, 0.3826834323650898f,
                        0.f, -0.3826834323650898f, -0.7071067811865476f, -0.9238795325112867f};
    const float S[8] = {0.f, 0.3826834323650898f, 0.7071067811865476f, 0.9238795325112867f,
                        1.f, 0.9238795325112867f, 0.7071067811865476f, 0.3826834323650898f};
    #pragma unroll
    for (int m = 1; m < 16; m <<= 1) {
        #pragma unroll
        for (int k = 0; k < 16; k += 2 * m) {
            #pragma unroll
            for (int j = 0; j < m; ++j) {
                float wc = C[j * (8 / m)], ws = S[j * (8 / m)];
                int i0 = k + j, i1 = i0 + m;
                float tr = re[i1] * wc - im[i1] * ws;
                float ti = re[i1] * ws + im[i1] * wc;
                re[i1] = re[i0] - tr; im[i1] = im[i0] - ti;
                re[i0] += tr;         im[i0] += ti;
            }
        }
    }
}

// -------- 256-pt inverse FFT over 8 rows in LDS, 128 threads --------
// In: fp32 natural order in lre/lim. Out: __half2(re,im) packed at
// ((__half2*)lre)[row*RS + n], natural order. Caller synced before.
__device__ __forceinline__ void fft256_block8(float* lre, float* lim, int tid) {
    const int r = tid >> 4, s = tid & 15;   // r 0..7
    float xr[16], xi[16];
    #pragma unroll
    for (int a = 0; a < 16; ++a) {
        xr[a] = lre[r * RS + 16 * a + s];
        xi[a] = lim[r * RS + 16 * a + s];
    }
    __syncthreads();
    fft16_reg(xr, xi);
    #pragma unroll
    for (int c = 0; c < 16; ++c) {
        float sn, cs;
        __sincosf(0.0245436926061703f * (float)(s * c), &sn, &cs); // 2*pi/256
        float tr = xr[c] * cs - xi[c] * sn;
        float ti = xr[c] * sn + xi[c] * cs;
        int idx = r * RS + 16 * c + (s ^ c);
        lre[idx] = tr; lim[idx] = ti;
    }
    __syncthreads();
    #pragma unroll
    for (int b = 0; b < 16; ++b) {
        int idx = r * RS + 16 * s + (b ^ s);
        xr[b] = lre[idx]; xi[b] = lim[idx];
    }
    __syncthreads();
    fft16_reg(xr, xi);
    // final values are fp16 in global anyway: pack here, aliasing lre (reads done)
    __half2* hb = (__half2*)lre;
    #pragma unroll
    for (int d = 0; d < 16; ++d)
        hb[r * RS + 16 * d + s] = __floats2half2_rn(xr[d], xi[d]);
    __syncthreads();
}

// ---------------- device bodies (shared by merged + fallback kernels) ----------------
__device__ __forceinline__ void dev_p1_xy(int bg, const float4* __restrict__ Fre4,
        const float4* __restrict__ Fim4, float alpha, uint4* __restrict__ GT4,
        int Sd4, int Sa4, float* lre, float* lim, int tid)
{
    const int d = bg & 7, ag = (bg >> 3) & 31, f = bg >> 8;
    const int a0 = ag * 8, c = f * 8 + d;
    const int base4 = f * 131072 + d * Sd4 + a0 * Sa4;
    #pragma unroll
    for (int j = 0; j < 4; ++j) {
        int i4 = tid + 128 * j;
        int ar = i4 >> 6, b4 = i4 & 63;
        float4 vr = Fre4[base4 + ar * Sa4 + b4];
        float4 vi = Fim4[base4 + ar * Sa4 + b4];
        int o = ar * RS + 4 * b4;
        *(float4*)&lre[o] = make_float4(vr.x*alpha, vr.y*alpha, vr.z*alpha, vr.w*alpha);
        *(float4*)&lim[o] = make_float4(vi.x*alpha, vi.y*alpha, vi.z*alpha, vi.w*alpha);
    }
    __syncthreads();
    fft256_block8(lre, lim, tid);
    const unsigned* hw = (const unsigned*)lre;
    const int g = tid >> 1, rq = tid & 1;
    #pragma unroll
    for (int j = 0; j < 4; ++j) {
        int k = g + 64 * j;
        uint4 ov = make_uint4(hw[(4*rq+0)*RS + k], hw[(4*rq+1)*RS + k],
                              hw[(4*rq+2)*RS + k], hw[(4*rq+3)*RS + k]);
        GT4[c * 16384 + k * 64 + ag * 2 + rq] = ov;
    }
}

__device__ __forceinline__ void dev_p2_xy(int bg, const uint4* __restrict__ GT4,
        uint4* __restrict__ V4, float* lre, float* lim, int tid)
{
    const int cg = bg & 15, b = bg >> 4, c0 = cg * 8;
    #pragma unroll
    for (int j = 0; j < 4; ++j) {
        int i4 = tid + 128 * j;
        int cr = i4 >> 6, a4 = i4 & 63;
        uint4 gv = GT4[(c0 + cr) * 16384 + b * 64 + a4];
        int o = cr * RS + 4 * a4;
        float2 e;
        e = __half22float2(bch(gv.x)); lre[o+0]=e.x; lim[o+0]=e.y;
        e = __half22float2(bch(gv.y)); lre[o+1]=e.x; lim[o+1]=e.y;
        e = __half22float2(bch(gv.z)); lre[o+2]=e.x; lim[o+2]=e.y;
        e = __half22float2(bch(gv.w)); lre[o+3]=e.x; lim[o+3]=e.y;
    }
    __syncthreads();
    fft256_block8(lre, lim, tid);
    const unsigned* hw = (const unsigned*)lre;
    const int g = tid >> 1, rq = tid & 1;
    #pragma unroll
    for (int j = 0; j < 4; ++j) {
        int k = g + 64 * j;
        uint4 ov = make_uint4(hw[(4*rq+0)*RS + k], hw[(4*rq+1)*RS + k],
                              hw[(4*rq+2)*RS + k], hw[(4*rq+3)*RS + k]);
        V4[(b * 256 + k) * 32 + cg * 2 + rq] = ov;
    }
}

__device__ __forceinline__ void dev_p1_z(int bg, const float4* __restrict__ Fre4,
        const float4* __restrict__ Fim4, float alpha, uint4* __restrict__ GTz4,
        float* lre, float* lim, int tid)
{
    const int f = bg >> 8, kx = bg & 255;
    const int base4 = f * 131072 + kx * 512;
    #pragma unroll
    for (int j = 0; j < 4; ++j) {
        int i4 = tid + 128 * j;
        int ky = i4 >> 1, t0 = i4 & 1;
        float4 vr = Fre4[base4 + i4];
        float4 vi = Fim4[base4 + i4];
        int r0 = 4 * t0;
        lre[(r0+0)*RS + ky] = vr.x*alpha; lim[(r0+0)*RS + ky] = vi.x*alpha;
        lre[(r0+1)*RS + ky] = vr.y*alpha; lim[(r0+1)*RS + ky] = vi.y*alpha;
        lre[(r0+2)*RS + ky] = vr.z*alpha; lim[(r0+2)*RS + ky] = vi.z*alpha;
        lre[(r0+3)*RS + ky] = vr.w*alpha; lim[(r0+3)*RS + ky] = vi.w*alpha;
    }
    __syncthreads();
    fft256_block8(lre, lim, tid);
    const unsigned* hw = (const unsigned*)lre;
    const int g = tid >> 1, rq = tid & 1;
    #pragma unroll
    for (int j = 0; j < 4; ++j) {
        int k = g + 64 * j;
        uint4 ov = make_uint4(hw[(4*rq+0)*RS + k], hw[(4*rq+1)*RS + k],
                              hw[(4*rq+2)*RS + k], hw[(4*rq+3)*RS + k]);
        GTz4[k * 8192 + f * 512 + kx * 2 + rq] = ov;
    }
}

__device__ __forceinline__ void dev_p2_z(int bg, const uint4* __restrict__ GTz4,
        uint4* __restrict__ V4, float* lre, float* lim, int tid)
{
    const int fg = bg & 15, b = bg >> 4;
    const int base4 = b * 8192 + fg * 512;
    #pragma unroll
    for (int j = 0; j < 4; ++j) {
        int i4 = tid + 128 * j;
        int kx = i4 >> 1, t0 = i4 & 1;
        uint4 gv = GTz4[base4 + i4];
        int r0 = 4 * t0;
        float2 e;
        e = __half22float2(bch(gv.x)); lre[(r0+0)*RS + kx]=e.x; lim[(r0+0)*RS + kx]=e.y;
        e = __half22float2(bch(gv.y)); lre[(r0+1)*RS + kx]=e.x; lim[(r0+1)*RS + kx]=e.y;
        e = __half22float2(bch(gv.z)); lre[(r0+2)*RS + kx]=e.x; lim[(r0+2)*RS + kx]=e.y;
        e = __half22float2(bch(gv.w)); lre[(r0+3)*RS + kx]=e.x; lim[(r0+3)*RS + kx]=e.y;
    }
    __syncthreads();
    fft256_block8(lre, lim, tid);
    const unsigned* hw = (const unsigned*)lre;
    const int g = tid >> 1, rq = tid & 1;
    #pragma unroll
    for (int j = 0; j < 4; ++j) {
        int k = g + 64 * j;
        uint4 ov = make_uint4(hw[(4*rq+0)*RS + k], hw[(4*rq+1)*RS + k],
                              hw[(4*rq+2)*RS + k], hw[(4*rq+3)*RS + k]);
        V4[(b * 256 + k) * 32 + fg * 2 + rq] = ov;
    }
}

// ---------------- merged kernels (big-ws path) ----------------
__global__ __launch_bounds__(128) void fft_pass1_all(
    const float4* __restrict__ Fxr, const float4* __restrict__ Fxi,
    const float4* __restrict__ Fyr, const float4* __restrict__ Fyi,
    const float4* __restrict__ Fzr, const float4* __restrict__ Fzi,
    const float* __restrict__ alpha_p,
    uint4* __restrict__ GTx, uint4* __restrict__ GTy, uint4* __restrict__ GTz)
{
    __shared__ __align__(16) float lre[8 * RS];
    __shared__ __align__(16) float lim[8 * RS];
    const int tid = threadIdx.x, bg = blockIdx.x;
    const float alpha = dev_alpha(alpha_p);
    if (bg < 4096)       dev_p1_xy(bg,        Fxr, Fxi, alpha, GTx, 16384, 64,  lre, lim, tid);
    else if (bg < 8192)  dev_p1_xy(bg - 4096, Fyr, Fyi, alpha, GTy, 64,    512, lre, lim, tid);
    else                 dev_p1_z (bg - 8192, Fzr, Fzi, alpha, GTz,            lre, lim, tid);
}

__global__ __launch_bounds__(128) void fft_pass2_all(
    const uint4* __restrict__ GTx, const uint4* __restrict__ GTy, const uint4* __restrict__ GTz,
    uint4* __restrict__ Vx, uint4* __restrict__ Vy, uint4* __restrict__ Vz)
{
    __shared__ __align__(16) float lre[8 * RS];
    __shared__ __align__(16) float lim[8 * RS];
    const int tid = threadIdx.x, bg = blockIdx.x;
    if (bg < 4096)       dev_p2_xy(bg,        GTx, Vx, lre, lim, tid);
    else if (bg < 8192)  dev_p2_xy(bg - 4096, GTy, Vy, lre, lim, tid);
    else                 dev_p2_z (bg - 8192, GTz, Vz, lre, lim, tid);
}

// ---------------- fallback single-dir kernels (small-ws path) ----------------
__global__ __launch_bounds__(128) void fft_p1xy_k(
    const float4* __restrict__ Fre4, const float4* __restrict__ Fim4,
    const float* __restrict__ alpha_p, uint4* __restrict__ GT4, int Sd4, int Sa4)
{
    __shared__ __align__(16) float lre[8 * RS];
    __shared__ __align__(16) float lim[8 * RS];
    dev_p1_xy(blockIdx.x, Fre4, Fim4, dev_alpha(alpha_p), GT4, Sd4, Sa4, lre, lim, threadIdx.x);
}
__global__ __launch_bounds__(128) void fft_p2xy_k(
    const uint4* __restrict__ GT4, uint4* __restrict__ V4)
{
    __shared__ __align__(16) float lre[8 * RS];
    __shared__ __align__(16) float lim[8 * RS];
    dev_p2_xy(blockIdx.x, GT4, V4, lre, lim, threadIdx.x);
}
__global__ __launch_bounds__(128) void fft_p1z_k(
    const float4* __restrict__ Fre4, const float4* __restrict__ Fim4,
    const float* __restrict__ alpha_p, uint4* __restrict__ GTz4)
{
    __shared__ __align__(16) float lre[8 * RS];
    __shared__ __align__(16) float lim[8 * RS];
    dev_p1_z(blockIdx.x, Fre4, Fim4, dev_alpha(alpha_p), GTz4, lre, lim, threadIdx.x);
}
__global__ __launch_bounds__(128) void fft_p2z_k(
    const uint4* __restrict__ GTz4, uint4* __restrict__ V4)
{
    __shared__ __align__(16) float lre[8 * RS];
    __shared__ __align__(16) float lim[8 * RS];
    dev_p2_z(blockIdx.x, GTz4, V4, lre, lim, threadIdx.x);
}

// ---------------- spatial sort (counting sort, key = zbin*256 + ybin) ----------------
__device__ __forceinline__ int bin8(float v) {
    return min(max((int)((v + 1.0f) * 127.5f), 0), 255);
}
__global__ __launch_bounds__(256) void zero_hist(unsigned* __restrict__ h) {
    h[blockIdx.x * 256 + threadIdx.x] = 0;
}
__global__ __launch_bounds__(256) void hist_k(const float* __restrict__ pts, unsigned* __restrict__ h) {
    int pid = blockIdx.x * 256 + threadIdx.x;
    int key = bin8(pts[pid * 3 + 2]) * 256 + bin8(pts[pid * 3 + 1]);
    atomicAdd(&h[key], 1u);
}
__global__ __launch_bounds__(256) void scan_k(const unsigned* __restrict__ h, unsigned* __restrict__ cur) {
    __shared__ unsigned part[256];
    const int t = threadIdx.x;
    unsigned sum = 0;
    for (int i = 0; i < 256; ++i) sum += h[t * 256 + i];
    part[t] = sum;
    __syncthreads();
    for (int o = 1; o < 256; o <<= 1) {
        unsigned v = part[t];
        unsigned add = (t >= o) ? part[t - o] : 0u;
        __syncthreads();
        part[t] = v + add;
        __syncthreads();
    }
    unsigned run = (t > 0) ? part[t - 1] : 0u;
    for (int i = 0; i < 256; ++i) {
        cur[t * 256 + i] = run;
        run += h[t * 256 + i];
    }
}
__global__ __launch_bounds__(256) void scatter_k(const float* __restrict__ pts,
                                                 unsigned* __restrict__ cur,
                                                 float4* __restrict__ ptsS) {
    int pid = blockIdx.x * 256 + threadIdx.x;
    float x = pts[pid * 3 + 0], y = pts[pid * 3 + 1], z = pts[pid * 3 + 2];
    int key = bin8(z) * 256 + bin8(y);
    unsigned pos = atomicAdd(&cur[key], 1u);
    ptsS[pos] = make_float4(x, y, z, __uint_as_float((unsigned)pid));
}

// ---------------- fused sampler: 2 points per wave, 4 channels per lane ----------------
__device__ __forceinline__ void bsample4(const uint4* __restrict__ V,
        float gx, float gy, bool swap, int L, float* re, float* im)
{
    float ix = (gx + 1.0f) * 127.5f;
    float iy = (gy + 1.0f) * 127.5f;
    float x0f = floorf(ix), y0f = floorf(iy);
    float wx = ix - x0f, wy = iy - y0f;
    int x0 = min(max((int)x0f, 0), 255);
    int x1 = min(x0 + 1, 255);
    int y0 = min(max((int)y0f, 0), 255);
    int y1 = min(y0 + 1, 255);
    int rA, rB, rC, rD;
    if (swap) { rA = y0*256+x0; rB = y0*256+x1; rC = y1*256+x0; rD = y1*256+x1; }
    else      { rA = x0*256+y0; rB = x1*256+y0; rC = x0*256+y1; rD = x1*256+y1; }
    uint4 A = V[rA * 32 + L];
    uint4 B = V[rB * 32 + L];
    uint4 C = V[rC * 32 + L];
    uint4 D = V[rD * 32 + L];
    __half2 w00 = __float2half2_rn((1.0f - wy) * (1.0f - wx));
    __half2 w01 = __float2half2_rn((1.0f - wy) * wx);
    __half2 w10 = __float2half2_rn(wy * (1.0f - wx));
    __half2 w11 = __float2half2_rn(wy * wx);
    __half2 a0 = __hmul2(w00, bch(A.x)), a1 = __hmul2(w00, bch(A.y));
    __half2 a2 = __hmul2(w00, bch(A.z)), a3 = __hmul2(w00, bch(A.w));
    a0 = __hfma2(w01, bch(B.x), a0); a1 = __hfma2(w01, bch(B.y), a1);
    a2 = __hfma2(w01, bch(B.z), a2); a3 = __hfma2(w01, bch(B.w), a3);
    a0 = __hfma2(w10, bch(C.x), a0); a1 = __hfma2(w10, bch(C.y), a1);
    a2 = __hfma2(w10, bch(C.z), a2); a3 = __hfma2(w10, bch(C.w), a3);
    a0 = __hfma2(w11, bch(D.x), a0); a1 = __hfma2(w11, bch(D.y), a1);
    a2 = __hfma2(w11, bch(D.z), a2); a3 = __hfma2(w11, bch(D.w), a3);
    float2 e;
    e = __half22float2(a0); re[0] = e.x; im[0] = e.y;
    e = __half22float2(a1); re[1] = e.x; im[1] = e.y;
    e = __half22float2(a2); re[2] = e.x; im[2] = e.y;
    e = __half22float2(a3); re[3] = e.x; im[3] = e.y;
}

__device__ __forceinline__ float irdft4(const float* re, const float* im, float tw, int L)
{
    const float TWO_PI = 6.28318530717958647692f;
    float xx = (tw + 1.0f) * 0.5f * (255.0f / 256.0f);
    float th = TWO_PI * xx;
    int d0 = (L & 1) * 4;
    float s0, c0, st, ct;
    __sincosf(th * (float)d0, &s0, &c0);
    __sincosf(th, &st, &ct);
    float c = c0, s = s0;
    float p = 0.f;
    #pragma unroll
    for (int i = 0; i < 4; ++i) {
        p += 2.0f * (re[i] * c - im[i] * s);
        float cn = c * ct - s * st;
        s = s * ct + c * st;
        c = cn;
    }
    if (d0 == 0) p -= re[0];  // k=0 harmonic scale is 1, not 2 (c0=1, s0=0 there)
    return p;
}

__global__ __launch_bounds__(256) void sample_all(
    const uint4* __restrict__ Vx, const uint4* __restrict__ Vy, const uint4* __restrict__ Vz,
    const float4* __restrict__ ptsS, float* __restrict__ out)
{
    const int lb = blockIdx.x;                       // 16384 blocks
    const int chunk = (lb & 7) * 2048 + (lb >> 3);   // XCD-contiguous sorted ranges
    const int tid = threadIdx.x;
    const int L = tid & 31;
    const int wid = chunk * 8 + (tid >> 5);
    float4 p = ptsS[wid];
    const float xs = p.x, ys = p.y, zs = p.z;
    const int pid = (int)__float_as_uint(p.w);

    float rex[4], imx[4], rey[4], imy[4], rez[4], imz[4];
    bsample4(Vx, zs, ys, false, L, rex, imx);
    bsample4(Vy, zs, xs, false, L, rey, imy);
    bsample4(Vz, xs, ys, true,  L, rez, imz);

    float pv = irdft4(rex, imx, xs, L) + irdft4(rey, imy, ys, L) + irdft4(rez, imz, zs, L);
    pv += __shfl_xor(pv, 1, 64);
    if ((L & 1) == 0) out[pid * 16 + (L >> 1)] = pv;
}

extern "C" void kernel_launch(void* const* d_in, const int* in_sizes, int n_in,
                              void* d_out, int out_size, void* d_ws, size_t ws_size,
                              hipStream_t stream) {
    const float* pts     = (const float*)d_in[0];
    const float4* Fxr    = (const float4*)d_in[1];
    const float4* Fxi    = (const float4*)d_in[2];
    const float4* Fyr    = (const float4*)d_in[3];
    const float4* Fyi    = (const float4*)d_in[4];
    const float4* Fzr    = (const float4*)d_in[5];
    const float4* Fzi    = (const float4*)d_in[6];
    const float* alpha_p = (const float*)d_in[7];
    float* out = (float*)d_out;

    char* ws = (char*)d_ws;
    const size_t MB = 1024 * 1024;
    uint4* Vx4 = (uint4*)(ws);
    uint4* Vy4 = (uint4*)(ws + 32 * MB);
    uint4* Vz4 = (uint4*)(ws + 64 * MB);

    size_t sortoff;
    if (ws_size >= (size_t)195 * MB) {
        uint4* GTx = (uint4*)(ws + 96 * MB);
        uint4* GTy = (uint4*)(ws + 128 * MB);
        uint4* GTz = (uint4*)(ws + 160 * MB);
        sortoff = 192 * MB;
        fft_pass1_all<<<12288, 128, 0, stream>>>(Fxr, Fxi, Fyr, Fyi, Fzr, Fzi, alpha_p,
                                                 GTx, GTy, GTz);
        fft_pass2_all<<<12288, 128, 0, stream>>>(GTx, GTy, GTz, Vx4, Vy4, Vz4);
    } else {
        uint4* GT = (uint4*)(ws + 96 * MB);
        sortoff = 96 * MB;   // sort scratch overlaps GT; sort runs after all FFTs
        fft_p1xy_k<<<4096, 128, 0, stream>>>(Fxr, Fxi, alpha_p, GT, 16384, 64);
        fft_p2xy_k<<<4096, 128, 0, stream>>>(GT, Vx4);
        fft_p1xy_k<<<4096, 128, 0, stream>>>(Fyr, Fyi, alpha_p, GT, 64, 512);
        fft_p2xy_k<<<4096, 128, 0, stream>>>(GT, Vy4);
        fft_p1z_k<<<4096, 128, 0, stream>>>(Fzr, Fzi, alpha_p, GT);
        fft_p2z_k<<<4096, 128, 0, stream>>>(GT, Vz4);
    }

    unsigned* hist = (unsigned*)(ws + sortoff);
    unsigned* cur  = (unsigned*)(ws + sortoff + 256 * 1024);
    float4*   ptsS = (float4*)  (ws + sortoff + 512 * 1024);
    zero_hist<<<256, 256, 0, stream>>>(hist);
    hist_k<<<NPTS / 256, 256, 0, stream>>>(pts, hist);
    scan_k<<<1, 256, 0, stream>>>(hist, cur);
    scatter_k<<<NPTS / 256, 256, 0, stream>>>(pts, cur, ptsS);

    sample_all<<<16384, 256, 0, stream>>>(Vx4, Vy4, Vz4, ptsS, out);
}

// Round 6
// 364.857 us; speedup vs baseline: 1.0731x; 1.0731x over previous
//
#include <hip/hip_runtime.h>
#include <hip/hip_fp16.h>
#include <math.h>

#define NPTS 131072
#define RSH 264  // LDS row stride in half2 (dword) units: 256 + 8 pad, rows 16B-aligned

__device__ __forceinline__ float dev_alpha(const float* __restrict__ ap) {
    float x = ap[0];
    float bx = 10.0f * x;
    if (bx > 1.0f) return x;
    float e = expf(fminf(bx, 30.0f));
    return 0.1f * log1pf(e);
}

__device__ __forceinline__ __half2 bch(unsigned u) { return __builtin_bit_cast(__half2, u); }
__device__ __forceinline__ unsigned packh2(float re, float im) {
    return __builtin_bit_cast(unsigned, __floats2half2_rn(re, im));
}
__device__ __forceinline__ void gload_lds16(const uint4* __restrict__ g, unsigned* l) {
    __builtin_amdgcn_global_load_lds((const __attribute__((address_space(1))) void*)g,
                                     (__attribute__((address_space(3))) void*)l, 16, 0, 0);
}

// -------- 16-point inverse DFT (e^{+i}) in registers, natural in/out --------
__device__ __forceinline__ void fft16_reg(float* re, float* im) {
    #define SW(a,b) { float t=re[a]; re[a]=re[b]; re[b]=t; t=im[a]; im[a]=im[b]; im[b]=t; }
    SW(1,8) SW(2,4) SW(3,12) SW(5,10) SW(7,14) SW(11,13)
    #undef SW
    const float C[8] = {1.f, 0.9238795325112867f, 0.7071067811865476f, 0.3826834323650898f,
                        0.f, -0.3826834323650898f, -0.7071067811865476f, -0.9238795325112867f};
    const float S[8] = {0.f, 0.3826834323650898f, 0.7071067811865476f, 0.9238795325112867f,
                        1.f, 0.9238795325112867f, 0.7071067811865476f, 0.3826834323650898f};
    #pragma unroll
    for (int m = 1; m < 16; m <<= 1) {
        #pragma unroll
        for (int k = 0; k < 16; k += 2 * m) {
            #pragma unroll
            for (int j = 0; j < m; ++j) {
                float wc = C[j * (8 / m)], ws = S[j * (8 / m)];
                int i0 = k + j, i1 = i0 + m;
                float tr = re[i1] * wc - im[i1] * ws;
                float ti = re[i1] * ws + im[i1] * wc;
                re[i1] = re[i0] - tr; im[i1] = im[i0] - ti;
                re[i0] += tr;         im[i0] += ti;
            }
        }
    }
}

// -------- 256-pt inverse FFT, 16 rows of half2 in LDS, wave-synchronous --------
// Each row (16 consecutive threads = quarter-wave) is independent: no block
// barriers needed inside. Input natural order; output natural order, scaled
// by `scale` (folded into the middle twiddle).
__device__ __forceinline__ void fft256_h2(unsigned* lds, int tid, float scale) {
    const int r = tid >> 4, s = tid & 15;
    unsigned* row = lds + r * RSH;
    float xr[16], xi[16];
    #pragma unroll
    for (int a = 0; a < 16; ++a) {
        float2 e = __half22float2(bch(row[16 * a + s]));
        xr[a] = e.x; xi[a] = e.y;
    }
    __builtin_amdgcn_wave_barrier();
    fft16_reg(xr, xi);
    // twiddle scale*e^{+2pi i s c/256} via recurrence, swizzled store
    float ct, st;
    __sincosf(0.0245436926061703f * (float)s, &st, &ct);
    float cc = scale, sc = 0.f;
    #pragma unroll
    for (int c = 0; c < 16; ++c) {
        float tr = xr[c] * cc - xi[c] * sc;
        float ti = xr[c] * sc + xi[c] * cc;
        row[16 * c + (s ^ c)] = packh2(tr, ti);
        float cn = cc * ct - sc * st;
        sc = sc * ct + cc * st;
        cc = cn;
    }
    __builtin_amdgcn_wave_barrier();
    #pragma unroll
    for (int b = 0; b < 16; ++b) {
        float2 e = __half22float2(bch(row[16 * s + (b ^ s)]));
        xr[b] = e.x; xi[b] = e.y;
    }
    __builtin_amdgcn_wave_barrier();
    fft16_reg(xr, xi);
    #pragma unroll
    for (int d = 0; d < 16; ++d)
        row[16 * d + s] = packh2(xr[d], xi[d]);
}

// shared writeout: uint4 = LDS rows 4rq..4rq+3 at col k -> dst4[recBase(k) + rq]
__device__ __forceinline__ void writeout16(const unsigned* lds, int tid,
                                           uint4* __restrict__ dst4,
                                           int recStride4, int recOff4) {
    const int g = tid >> 2, rq = tid & 3;
    #pragma unroll
    for (int j = 0; j < 4; ++j) {
        int k = g + 64 * j;
        uint4 ov = make_uint4(lds[(4 * rq + 0) * RSH + k], lds[(4 * rq + 1) * RSH + k],
                              lds[(4 * rq + 2) * RSH + k], lds[(4 * rq + 3) * RSH + k]);
        dst4[k * recStride4 + recOff4 + rq] = ov;
    }
}

// ---------------- pass1 xy: FFT along innermost kz -> GT[c][z][a] ----------------
__device__ __forceinline__ void p1_xy(int bg, const float4* __restrict__ Fre4,
        const float4* __restrict__ Fim4, float alpha, uint4* __restrict__ GT4,
        int Sd4, int Sa4, unsigned* lds, int tid)
{
    const int d = bg & 7, ag = (bg >> 3) & 15, f = bg >> 7;
    const int a0 = ag * 16, c = f * 8 + d;
    const int base4 = f * 131072 + d * Sd4 + a0 * Sa4;
    #pragma unroll
    for (int j = 0; j < 4; ++j) {
        int i4 = tid + 256 * j;
        int ar = i4 >> 6, b4 = i4 & 63;
        float4 vr = Fre4[base4 + ar * Sa4 + b4];
        float4 vi = Fim4[base4 + ar * Sa4 + b4];
        uint4 pk = make_uint4(packh2(vr.x, vi.x), packh2(vr.y, vi.y),
                              packh2(vr.z, vi.z), packh2(vr.w, vi.w));
        *(uint4*)&lds[ar * RSH + 4 * b4] = pk;
    }
    __syncthreads();
    fft256_h2(lds, tid, alpha);
    __syncthreads();
    // GT4[c*16384 + k*64 + ag*4 + rq]
    writeout16(lds, tid, GT4 + c * 16384, 64, ag * 4);
}

// ---------------- pass2 xy: FFT along a of GT[c][b][a] -> V[b][t][c] ----------------
__device__ __forceinline__ void p2_xy(int bg, const uint4* __restrict__ GT4,
        uint4* __restrict__ V4, unsigned* lds, int tid)
{
    const int cg = bg & 7, b = bg >> 3, c0 = cg * 16;
    const int wv = __builtin_amdgcn_readfirstlane(tid >> 6);
    const int lane = tid & 63;
    #pragma unroll
    for (int j = 0; j < 4; ++j) {
        int cr = wv * 4 + j;
        gload_lds16(GT4 + (c0 + cr) * 16384 + b * 64 + lane, &lds[cr * RSH]);
    }
    __syncthreads();
    fft256_h2(lds, tid, 1.0f);
    __syncthreads();
    // V4[(b*256+k)*32 + cg*4 + rq]
    writeout16(lds, tid, V4 + b * 8192, 32, cg * 4);
}

// ---------------- pass1 z: Fz[f][kx][ky][d] -> FFT ky -> GTz[y][f][kx][d] ----------------
__device__ __forceinline__ void p1_z(int bg, const float4* __restrict__ Fre4,
        const float4* __restrict__ Fim4, float alpha, uint4* __restrict__ GTz4,
        unsigned* lds, int tid)
{
    const int kxp = bg & 127, f = bg >> 7;
    const int base4 = f * 131072 + kxp * 1024;
    #pragma unroll
    for (int j = 0; j < 4; ++j) {
        int i4 = tid + 256 * j;
        int kxo = i4 >> 9, rem = i4 & 511;
        int ky = rem >> 1, t0 = rem & 1;
        float4 vr = Fre4[base4 + i4];
        float4 vi = Fim4[base4 + i4];
        int r0 = kxo * 8 + 4 * t0;
        lds[(r0 + 0) * RSH + ky] = packh2(vr.x, vi.x);
        lds[(r0 + 1) * RSH + ky] = packh2(vr.y, vi.y);
        lds[(r0 + 2) * RSH + ky] = packh2(vr.z, vi.z);
        lds[(r0 + 3) * RSH + ky] = packh2(vr.w, vi.w);
    }
    __syncthreads();
    fft256_h2(lds, tid, alpha);
    __syncthreads();
    // rows: kxo*8 + d ; uint4 rq -> (kxo=rq>>1, d=4*(rq&1)..) ; GTz4[k*8192 + f*512 + kxp*4 + rq]
    writeout16(lds, tid, GTz4 + f * 512, 8192, kxp * 4);
}

// ---------------- pass2 z: GTz[y][f][kx][d] -> FFT kx -> Vz[y][x][c] ----------------
__device__ __forceinline__ void p2_z(int bg, const uint4* __restrict__ GTz4,
        uint4* __restrict__ V4, unsigned* lds, int tid)
{
    const int fg = bg & 7, b = bg >> 3;
    const int base4 = b * 8192 + fg * 1024;
    #pragma unroll
    for (int j = 0; j < 4; ++j) {
        int i4 = tid + 256 * j;
        int fo = i4 >> 9, rem = i4 & 511;
        int kx = rem >> 1, t0 = rem & 1;
        uint4 gv = GTz4[base4 + i4];
        int r0 = fo * 8 + 4 * t0;
        lds[(r0 + 0) * RSH + kx] = gv.x;
        lds[(r0 + 1) * RSH + kx] = gv.y;
        lds[(r0 + 2) * RSH + kx] = gv.z;
        lds[(r0 + 3) * RSH + kx] = gv.w;
    }
    __syncthreads();
    fft256_h2(lds, tid, 1.0f);
    __syncthreads();
    writeout16(lds, tid, V4 + b * 8192, 32, fg * 4);
}

// ---------------- merged kernels (bgBase allows per-dir fallback launches) ----------------
__global__ __launch_bounds__(256, 4) void fft_pass1_all(
    const float4* __restrict__ Fxr, const float4* __restrict__ Fxi,
    const float4* __restrict__ Fyr, const float4* __restrict__ Fyi,
    const float4* __restrict__ Fzr, const float4* __restrict__ Fzi,
    const float* __restrict__ alpha_p,
    uint4* __restrict__ GTx, uint4* __restrict__ GTy, uint4* __restrict__ GTz,
    int bgBase)
{
    __shared__ __align__(16) unsigned lds[16 * RSH];
    const int tid = threadIdx.x;
    const int bg = blockIdx.x + bgBase;
    const float alpha = dev_alpha(alpha_p);
    if (bg < 2048)       p1_xy(bg,        Fxr, Fxi, alpha, GTx, 16384, 64,  lds, tid);
    else if (bg < 4096)  p1_xy(bg - 2048, Fyr, Fyi, alpha, GTy, 64,    512, lds, tid);
    else                 p1_z (bg - 4096, Fzr, Fzi, alpha, GTz,            lds, tid);
}

__global__ __launch_bounds__(256, 4) void fft_pass2_all(
    const uint4* __restrict__ GTx, const uint4* __restrict__ GTy, const uint4* __restrict__ GTz,
    uint4* __restrict__ Vx, uint4* __restrict__ Vy, uint4* __restrict__ Vz,
    int bgBase)
{
    __shared__ __align__(16) unsigned lds[16 * RSH];
    const int tid = threadIdx.x;
    const int bg = blockIdx.x + bgBase;
    if (bg < 2048)       p2_xy(bg,        GTx, Vx, lds, tid);
    else if (bg < 4096)  p2_xy(bg - 2048, GTy, Vy, lds, tid);
    else                 p2_z (bg - 4096, GTz, Vz, lds, tid);
}

// ---------------- spatial sort (counting sort, key = zbin*256 + ybin) ----------------
__device__ __forceinline__ int bin8(float v) {
    return min(max((int)((v + 1.0f) * 127.5f), 0), 255);
}
__global__ __launch_bounds__(256) void zero_hist(unsigned* __restrict__ h) {
    h[blockIdx.x * 256 + threadIdx.x] = 0;
}
__global__ __launch_bounds__(256) void hist_k(const float* __restrict__ pts, unsigned* __restrict__ h) {
    int pid = blockIdx.x * 256 + threadIdx.x;
    int key = bin8(pts[pid * 3 + 2]) * 256 + bin8(pts[pid * 3 + 1]);
    atomicAdd(&h[key], 1u);
}
__global__ __launch_bounds__(256) void scan_k(const unsigned* __restrict__ h, unsigned* __restrict__ cur) {
    __shared__ unsigned part[256];
    const int t = threadIdx.x;
    unsigned sum = 0;
    for (int i = 0; i < 256; ++i) sum += h[t * 256 + i];
    part[t] = sum;
    __syncthreads();
    for (int o = 1; o < 256; o <<= 1) {
        unsigned v = part[t];
        unsigned add = (t >= o) ? part[t - o] : 0u;
        __syncthreads();
        part[t] = v + add;
        __syncthreads();
    }
    unsigned run = (t > 0) ? part[t - 1] : 0u;
    for (int i = 0; i < 256; ++i) {
        cur[t * 256 + i] = run;
        run += h[t * 256 + i];
    }
}
__global__ __launch_bounds__(256) void scatter_k(const float* __restrict__ pts,
                                                 unsigned* __restrict__ cur,
                                                 float4* __restrict__ ptsS) {
    int pid = blockIdx.x * 256 + threadIdx.x;
    float x = pts[pid * 3 + 0], y = pts[pid * 3 + 1], z = pts[pid * 3 + 2];
    int key = bin8(z) * 256 + bin8(y);
    unsigned pos = atomicAdd(&cur[key], 1u);
    ptsS[pos] = make_float4(x, y, z, __uint_as_float((unsigned)pid));
}

// ---------------- fused sampler: 2 points per wave, 4 channels per lane ----------------
__device__ __forceinline__ void bsample4(const uint4* __restrict__ V,
        float gx, float gy, bool swap, int L, float* re, float* im)
{
    float ix = (gx + 1.0f) * 127.5f;
    float iy = (gy + 1.0f) * 127.5f;
    float x0f = floorf(ix), y0f = floorf(iy);
    float wx = ix - x0f, wy = iy - y0f;
    int x0 = min(max((int)x0f, 0), 255);
    int x1 = min(x0 + 1, 255);
    int y0 = min(max((int)y0f, 0), 255);
    int y1 = min(y0 + 1, 255);
    int rA, rB, rC, rD;
    if (swap) { rA = y0*256+x0; rB = y0*256+x1; rC = y1*256+x0; rD = y1*256+x1; }
    else      { rA = x0*256+y0; rB = x1*256+y0; rC = x0*256+y1; rD = x1*256+y1; }
    uint4 A = V[rA * 32 + L];
    uint4 B = V[rB * 32 + L];
    uint4 C = V[rC * 32 + L];
    uint4 D = V[rD * 32 + L];
    __half2 w00 = __float2half2_rn((1.0f - wy) * (1.0f - wx));
    __half2 w01 = __float2half2_rn((1.0f - wy) * wx);
    __half2 w10 = __float2half2_rn(wy * (1.0f - wx));
    __half2 w11 = __float2half2_rn(wy * wx);
    __half2 a0 = __hmul2(w00, bch(A.x)), a1 = __hmul2(w00, bch(A.y));
    __half2 a2 = __hmul2(w00, bch(A.z)), a3 = __hmul2(w00, bch(A.w));
    a0 = __hfma2(w01, bch(B.x), a0); a1 = __hfma2(w01, bch(B.y), a1);
    a2 = __hfma2(w01, bch(B.z), a2); a3 = __hfma2(w01, bch(B.w), a3);
    a0 = __hfma2(w10, bch(C.x), a0); a1 = __hfma2(w10, bch(C.y), a1);
    a2 = __hfma2(w10, bch(C.z), a2); a3 = __hfma2(w10, bch(C.w), a3);
    a0 = __hfma2(w11, bch(D.x), a0); a1 = __hfma2(w11, bch(D.y), a1);
    a2 = __hfma2(w11, bch(D.z), a2); a3 = __hfma2(w11, bch(D.w), a3);
    float2 e;
    e = __half22float2(a0); re[0] = e.x; im[0] = e.y;
    e = __half22float2(a1); re[1] = e.x; im[1] = e.y;
    e = __half22float2(a2); re[2] = e.x; im[2] = e.y;
    e = __half22float2(a3); re[3] = e.x; im[3] = e.y;
}

__device__ __forceinline__ float irdft4(const float* re, const float* im, float tw, int L)
{
    const float TWO_PI = 6.28318530717958647692f;
    float xx = (tw + 1.0f) * 0.5f * (255.0f / 256.0f);
    float th = TWO_PI * xx;
    int d0 = (L & 1) * 4;
    float s0, c0, st, ct;
    __sincosf(th * (float)d0, &s0, &c0);
    __sincosf(th, &st, &ct);
    float c = c0, s = s0;
    float p = 0.f;
    #pragma unroll
    for (int i = 0; i < 4; ++i) {
        p += 2.0f * (re[i] * c - im[i] * s);
        float cn = c * ct - s * st;
        s = s * ct + c * st;
        c = cn;
    }
    if (d0 == 0) p -= re[0];  // k=0 harmonic scale is 1, not 2
    return p;
}

__global__ __launch_bounds__(256) void sample_all(
    const uint4* __restrict__ Vx, const uint4* __restrict__ Vy, const uint4* __restrict__ Vz,
    const float4* __restrict__ ptsS, float* __restrict__ out)
{
    const int lb = blockIdx.x;                       // 16384 blocks
    const int chunk = (lb & 7) * 2048 + (lb >> 3);   // XCD-contiguous sorted ranges
    const int tid = threadIdx.x;
    const int L = tid & 31;
    const int wid = chunk * 8 + (tid >> 5);
    float4 p = ptsS[wid];
    const float xs = p.x, ys = p.y, zs = p.z;
    const int pid = (int)__float_as_uint(p.w);

    float rex[4], imx[4], rey[4], imy[4], rez[4], imz[4];
    bsample4(Vx, zs, ys, false, L, rex, imx);
    bsample4(Vy, zs, xs, false, L, rey, imy);
    bsample4(Vz, xs, ys, true,  L, rez, imz);

    float pv = irdft4(rex, imx, xs, L) + irdft4(rey, imy, ys, L) + irdft4(rez, imz, zs, L);
    pv += __shfl_xor(pv, 1, 64);
    if ((L & 1) == 0) out[pid * 16 + (L >> 1)] = pv;
}

extern "C" void kernel_launch(void* const* d_in, const int* in_sizes, int n_in,
                              void* d_out, int out_size, void* d_ws, size_t ws_size,
                              hipStream_t stream) {
    const float* pts     = (const float*)d_in[0];
    const float4* Fxr    = (const float4*)d_in[1];
    const float4* Fxi    = (const float4*)d_in[2];
    const float4* Fyr    = (const float4*)d_in[3];
    const float4* Fyi    = (const float4*)d_in[4];
    const float4* Fzr    = (const float4*)d_in[5];
    const float4* Fzi    = (const float4*)d_in[6];
    const float* alpha_p = (const float*)d_in[7];
    float* out = (float*)d_out;

    char* ws = (char*)d_ws;
    const size_t MB = 1024 * 1024;
    uint4* Vx4 = (uint4*)(ws);
    uint4* Vy4 = (uint4*)(ws + 32 * MB);
    uint4* Vz4 = (uint4*)(ws + 64 * MB);

    size_t sortoff;
    if (ws_size >= (size_t)195 * MB) {
        uint4* GTx = (uint4*)(ws + 96 * MB);
        uint4* GTy = (uint4*)(ws + 128 * MB);
        uint4* GTz = (uint4*)(ws + 160 * MB);
        sortoff = 192 * MB;
        fft_pass1_all<<<6144, 256, 0, stream>>>(Fxr, Fxi, Fyr, Fyi, Fzr, Fzi, alpha_p,
                                                GTx, GTy, GTz, 0);
        fft_pass2_all<<<6144, 256, 0, stream>>>(GTx, GTy, GTz, Vx4, Vy4, Vz4, 0);
    } else {
        uint4* GT = (uint4*)(ws + 96 * MB);
        sortoff = 96 * MB;   // sort scratch overlaps GT; sort runs after all FFTs
        for (int dir = 0; dir < 3; ++dir) {
            fft_pass1_all<<<2048, 256, 0, stream>>>(Fxr, Fxi, Fyr, Fyi, Fzr, Fzi, alpha_p,
                                                    GT, GT, GT, dir * 2048);
            fft_pass2_all<<<2048, 256, 0, stream>>>(GT, GT, GT, Vx4, Vy4, Vz4, dir * 2048);
        }
    }

    unsigned* hist = (unsigned*)(ws + sortoff);
    unsigned* cur  = (unsigned*)(ws + sortoff + 256 * 1024);
    float4*   ptsS = (float4*)  (ws + sortoff + 512 * 1024);
    zero_hist<<<256, 256, 0, stream>>>(hist);
    hist_k<<<NPTS / 256, 256, 0, stream>>>(pts, hist);
    scan_k<<<1, 256, 0, stream>>>(hist, cur);
    scatter_k<<<NPTS / 256, 256, 0, stream>>>(pts, cur, ptsS);

    sample_all<<<16384, 256, 0, stream>>>(Vx4, Vy4, Vz4, ptsS, out);
}